// Round 3
// baseline (754.718 us; speedup 1.0000x reference)
//
#include <hip/hip_runtime.h>
#include <stdint.h>

typedef _Float16 half8 __attribute__((ext_vector_type(8)));
typedef float f32x4 __attribute__((ext_vector_type(4)));

typedef const __attribute__((address_space(1))) void* gptr_t;
typedef __attribute__((address_space(3))) void* lptr_t;
static __device__ __forceinline__ void gll16(const void* g, void* l) {
  __builtin_amdgcn_global_load_lds((gptr_t)(unsigned long long)g,
                                   (lptr_t)(unsigned int)(unsigned long long)l,
                                   16, 0, 0);
}

// ---------------- Cheb chain, one block ----------------
__global__ __launch_bounds__(1024)
void k_cheb_all(const float* __restrict__ x, const int* __restrict__ ei,
                float* __restrict__ Tx) {
  __shared__ float deg[1024];
  __shared__ float wn[2048];
  __shared__ float T0[4096], T1[4096], yv[4096];
  int t = threadIdx.x;
  deg[t] = 0.f;
  __syncthreads();
  atomicAdd(&deg[ei[t]], 1.f);
  atomicAdd(&deg[ei[1024 + t]], 1.f);
  __syncthreads();
  for (int e = t; e < 2048; e += 1024) {
    int s = ei[e], d = ei[2048 + e];
    float ds = deg[s], dd = deg[d];
    float a = ds > 0.f ? 1.f / sqrtf(fmaxf(ds, 1.f)) : 0.f;
    float b = dd > 0.f ? 1.f / sqrtf(fmaxf(dd, 1.f)) : 0.f;
    wn[e] = -a * b;
  }
  float4 xv = ((const float4*)x)[t];
  ((float4*)T0)[t] = xv;
  ((float4*)Tx)[t] = xv;
  __syncthreads();
  float* cur = T0; float* nxt = T1;
  for (int rec = 0; rec < 4; ++rec) {
    ((float4*)yv)[t] = make_float4(0.f, 0.f, 0.f, 0.f);
    __syncthreads();
    for (int e = t; e < 2048; e += 1024) {
      int s = ei[e], d = ei[2048 + e];
      float wv = wn[e];
#pragma unroll
      for (int c = 0; c < 4; ++c) atomicAdd(&yv[d * 4 + c], wv * cur[s * 4 + c]);
    }
    __syncthreads();
    float a = (rec == 0) ? 1.f : 2.f;
    float4 y4 = ((float4*)yv)[t];
    float4 p4 = ((float4*)nxt)[t];
    float4 n4;
    n4.x = a * y4.x - (rec ? p4.x : 0.f);
    n4.y = a * y4.y - (rec ? p4.y : 0.f);
    n4.z = a * y4.z - (rec ? p4.z : 0.f);
    n4.w = a * y4.w - (rec ? p4.w : 0.f);
    ((float4*)nxt)[t] = n4;
    ((float4*)(Tx + (rec + 1) * 4096))[t] = n4;
    __syncthreads();
    float* tmp = cur; cur = nxt; nxt = tmp;
  }
}

__global__ void k_cheb_out(const float* __restrict__ Tx, const float* __restrict__ cw,
                           const float* __restrict__ cb, float* __restrict__ h) {
  int n = blockIdx.x, o = threadIdx.x;
  float acc = cb[o];
#pragma unroll
  for (int k = 0; k < 5; ++k)
#pragma unroll
    for (int c = 0; c < 4; ++c)
      acc += Tx[k * 4096 + n * 4 + c] * cw[(k * 4 + c) * 192 + o];
  h[n * 192 + o] = acc;
}

__global__ void k_ea(const float* __restrict__ eattr, const float* __restrict__ ew,
                     const float* __restrict__ ebv, float* __restrict__ ea) {
  int e = blockIdx.x, o = threadIdx.x;
  float acc = ebv[o];
#pragma unroll
  for (int c = 0; c < 4; ++c) acc += eattr[e * 4 + c] * ew[c * 192 + o];
  ea[e * 192 + o] = acc;
}

// ---------- unified weight transpose: f32 [192 x ...] -> f16 chunk layout ----------
// chunk unit (ck=kk/8): halfs (ck*192 + o)*8 + (kk&7), units of 1536 halfs
__global__ void k_tr(const float* __restrict__ nn2_w, const float* __restrict__ nn1_w,
                     const float* __restrict__ nn2_b, const float* __restrict__ root_w,
                     _Float16* __restrict__ nn2t, _Float16* __restrict__ nn1t,
                     _Float16* __restrict__ b2t, _Float16* __restrict__ rwt) {
  __shared__ float tl[192 * 65];
  int gx = blockIdx.x;
  int l = gx / 195, g = gx % 195;
  int o0 = blockIdx.y * 64, t = threadIdx.x;
  const float* src; size_t rstride; _Float16* dst;
  if (g < 192) {
    src = nn2_w + (size_t)l * 7077888 + (size_t)g * 192; rstride = 36864;
    dst = nn2t + ((size_t)l * 4608 + (size_t)g * 24) * 1536;
  } else if (g == 192) {
    src = nn1_w + (size_t)l * 36864; rstride = 192; dst = nn1t + (size_t)l * 36864;
  } else if (g == 193) {
    src = nn2_b + (size_t)l * 36864; rstride = 192; dst = b2t + (size_t)l * 36864;
  } else {
    src = root_w + (size_t)l * 36864; rstride = 192; dst = rwt + (size_t)l * 36864;
  }
#pragma unroll
  for (int it = 0; it < 48; ++it) {
    int idx = it * 256 + t; int kk = idx >> 6, o = idx & 63;
    tl[kk * 65 + o] = src[(size_t)kk * rstride + o0 + o];
  }
  __syncthreads();
#pragma unroll
  for (int it = 0; it < 6; ++it) {
    int idx = it * 256 + t; int ck = idx >> 6, o = idx & 63;
    union { _Float16 h[8]; uint4 v; } u;
#pragma unroll
    for (int j = 0; j < 8; ++j) u.h[j] = (_Float16)tl[(ck * 8 + j) * 65 + o];
    *(uint4*)(dst + ((size_t)ck * 192 + o0 + o) * 8) = u.v;
  }
}

// ---------- per-layer edge prep: gather zsT (f16, [i][e]) + zero agg ----------
__global__ void k_edge(const int* __restrict__ ei, const float* __restrict__ z,
                       _Float16* __restrict__ zsT, float* __restrict__ agg) {
  __shared__ float tl[64 * 193];
  int e0 = blockIdx.x * 64, t = threadIdx.x;
  float4 zf = make_float4(0.f, 0.f, 0.f, 0.f);
#pragma unroll
  for (int q = 0; q < 6; ++q) ((float4*)agg)[blockIdx.x * 1536 + q * 256 + t] = zf;
#pragma unroll
  for (int it = 0; it < 48; ++it) {
    int idx = it * 256 + t; int es = idx / 192, i = idx - es * 192;
    tl[es * 193 + i] = z[(size_t)ei[e0 + es] * 192 + i];
  }
  __syncthreads();
#pragma unroll
  for (int it = 0; it < 48; ++it) {
    int idx = it * 256 + t; int i = idx >> 6, es = idx & 63;
    zsT[(size_t)i * 2048 + e0 + es] = (_Float16)tl[es * 193 + i];
  }
}

// ---------- unified small MFMA GEMM: C[M,192] = A[M,192] @ B + epilogue ----------
// 256 thr = 4 waves, wave = 32 rows x 192 cols. modes: 0=h2(all layers), 1=nodeMsg, 2=node(root+LN)
__global__ __launch_bounds__(256, 2)
void k_ng(const float* __restrict__ A, const _Float16* __restrict__ Bt0,
          const float* __restrict__ bias, _Float16* __restrict__ h2out,
          const float* __restrict__ aggp, const float* __restrict__ cbp,
          float* __restrict__ hio, const float* __restrict__ lng,
          const float* __restrict__ lnb, float* __restrict__ fout,
          int mode, int res) {
  extern __shared__ _Float16 sm[];
  _Float16* Al = sm;            // 24 ck * 128 rows * 8 halfs
  _Float16* Bl = sm + 24576;    // 2 * 6144 halfs
  int t = threadIdx.x;
  int w = t >> 6, lane = t & 63, l15 = lane & 15, q4 = lane >> 4;
  int e0 = blockIdx.x * 128;
  int ly = blockIdx.y;
  const _Float16* Bt = Bt0 + (mode == 0 ? (size_t)ly * 36864 : 0);
  // prefetch B chunk 0
#pragma unroll
  for (int q = 0; q < 3; ++q)
    gll16((const char*)Bt + (q * 256 + t) * 16, (char*)Bl + (q * 256 + t) * 16);
  // stage A as f16 chunk-major
#pragma unroll
  for (int it = 0; it < 12; ++it) {
    int u = it * 256 + t;
    int row = u / 24, ck = u - row * 24;
    const float* ap = A + (size_t)(e0 + row) * 192 + ck * 8;
    float4 v0 = *(const float4*)ap;
    float4 v1 = *(const float4*)(ap + 4);
    union { _Float16 h[8]; uint4 v; } uu;
    uu.h[0] = (_Float16)v0.x; uu.h[1] = (_Float16)v0.y;
    uu.h[2] = (_Float16)v0.z; uu.h[3] = (_Float16)v0.w;
    uu.h[4] = (_Float16)v1.x; uu.h[5] = (_Float16)v1.y;
    uu.h[6] = (_Float16)v1.z; uu.h[7] = (_Float16)v1.w;
    *(uint4*)(Al + ((size_t)ck * 128 + row) * 8) = uu.v;
  }
  __syncthreads();

  f32x4 acc[2][12] = {};
  int buf = 0;
  for (int ks = 0; ks < 6; ++ks) {
    if (ks < 5) {
      const char* gp = (const char*)Bt + (ks + 1) * 12288;
      char* lp = (char*)(Bl + (buf ^ 1) * 6144);
#pragma unroll
      for (int q = 0; q < 3; ++q)
        gll16(gp + (q * 256 + t) * 16, lp + (q * 256 + t) * 16);
    }
    half8 av[2];
#pragma unroll
    for (int mt = 0; mt < 2; ++mt) {
      int row = w * 32 + mt * 16 + l15;
      av[mt] = *(const half8*)(Al + (((ks * 4 + q4) * 128) + row) * 8);
    }
#pragma unroll
    for (int nt = 0; nt < 12; ++nt) {
      half8 bv = *(const half8*)(Bl + buf * 6144 + ((q4 * 192) + nt * 16 + l15) * 8);
#pragma unroll
      for (int mt = 0; mt < 2; ++mt)
        acc[mt][nt] = __builtin_amdgcn_mfma_f32_16x16x32_f16(av[mt], bv, acc[mt][nt], 0, 0, 0);
    }
    __syncthreads();
    buf ^= 1;
  }

  if (mode == 0) {
    // + bias, emit f16 chunk-major h2p (transpose via LDS reuse)
#pragma unroll
    for (int mt = 0; mt < 2; ++mt)
#pragma unroll
      for (int nt = 0; nt < 12; ++nt) {
        int col = nt * 16 + l15;
        float bv = bias[(size_t)ly * 192 + col];
#pragma unroll
        for (int r = 0; r < 4; ++r) {
          int row = w * 32 + mt * 16 + q4 * 4 + r;
          Al[((size_t)(col >> 3) * 128 + row) * 8 + (col & 7)] = (_Float16)(acc[mt][nt][r] + bv);
        }
      }
    __syncthreads();
    _Float16* ho = h2out + (size_t)ly * 393216;
#pragma unroll
    for (int it = 0; it < 12; ++it) {
      int u = it * 256 + t; int ck = u >> 7, row = u & 127;
      *(uint4*)(ho + ((size_t)ck * 2048 + (e0 + row)) * 8) = *(const uint4*)(Al + ((size_t)ck * 128 + row) * 8);
    }
  } else if (mode == 1) {
#pragma unroll
    for (int mt = 0; mt < 2; ++mt)
#pragma unroll
      for (int nt = 0; nt < 12; ++nt) {
        int col = nt * 16 + l15;
#pragma unroll
        for (int r = 0; r < 4; ++r) {
          int row = e0 + w * 32 + mt * 16 + q4 * 4 + r;
          fout[(size_t)row * 192 + col] = acc[mt][nt][r];
        }
      }
  } else {
    // node: + agg + cb (+h residual) -> hio; LN+relu -> fout
    float s1[2][4] = {}, s2[2][4] = {};
#pragma unroll
    for (int mt = 0; mt < 2; ++mt)
#pragma unroll
      for (int nt = 0; nt < 12; ++nt) {
        int col = nt * 16 + l15;
        float cbv = cbp[col];
#pragma unroll
        for (int r = 0; r < 4; ++r) {
          int row = e0 + w * 32 + mt * 16 + q4 * 4 + r;
          float v = acc[mt][nt][r] + aggp[(size_t)row * 192 + col] + cbv;
          if (res) v += hio[(size_t)row * 192 + col];
          hio[(size_t)row * 192 + col] = v;
          acc[mt][nt][r] = v;
          s1[mt][r] += v; s2[mt][r] += v * v;
        }
      }
#pragma unroll
    for (int m = 1; m < 16; m <<= 1)
#pragma unroll
      for (int mt = 0; mt < 2; ++mt)
#pragma unroll
        for (int r = 0; r < 4; ++r) {
          s1[mt][r] += __shfl_xor(s1[mt][r], m);
          s2[mt][r] += __shfl_xor(s2[mt][r], m);
        }
    float rs[2][4], mu[2][4];
#pragma unroll
    for (int mt = 0; mt < 2; ++mt)
#pragma unroll
      for (int r = 0; r < 4; ++r) {
        float m1 = s1[mt][r] / 192.f;
        float var = s2[mt][r] / 192.f - m1 * m1;
        mu[mt][r] = m1; rs[mt][r] = rsqrtf(var + 1e-5f);
      }
#pragma unroll
    for (int mt = 0; mt < 2; ++mt)
#pragma unroll
      for (int nt = 0; nt < 12; ++nt) {
        int col = nt * 16 + l15;
        float gv = lng[col], bv = lnb[col];
#pragma unroll
        for (int r = 0; r < 4; ++r) {
          int row = e0 + w * 32 + mt * 16 + q4 * 4 + r;
          float zv = (acc[mt][nt][r] - mu[mt][r]) * rs[mt][r] * gv + bv;
          fout[(size_t)row * 192 + col] = fmaxf(zv, 0.f);
        }
      }
  }
}

// ---------------- big fused GEMM (theta contraction) ----------------
// grid (32 k-chunks, 16 m-blocks): same-k blocks share XCD => B slab L2-resident
__global__ __launch_bounds__(512, 4)
void k_big2(const _Float16* __restrict__ h2l, const _Float16* __restrict__ btl,
            const _Float16* __restrict__ zsT, _Float16* __restrict__ partial) {
  extern __shared__ _Float16 sm[];
  _Float16* Al = sm;           // 24 * 128 * 8
  _Float16* Bl = sm + 24576;   // 2 * 6144

  const int tid = threadIdx.x;
  const int w = tid >> 6, lane = tid & 63;
  const int l15 = lane & 15, q4 = lane >> 4;
  const int wm = w >> 2, wn = w & 3;
  const int s = blockIdx.x;
  const int e0 = blockIdx.y * 128;
  const int i0 = s * 6;
  const int sg0 = s * 36;

#pragma unroll
  for (int t = 0; t < 6; ++t) {
    int fo = (t * 8 + w) * 1024 + lane * 16;
    int q = fo >> 11;
    const _Float16* g = h2l + (size_t)q * 16384 + (size_t)e0 * 8 + ((fo & 2047) >> 1);
    gll16(g, (char*)Al + fo);
  }
  {
    const char* g = (const char*)btl + (size_t)sg0 * 12288 + w * 1024 + lane * 16;
    char* l = (char*)Bl + w * 1024 + lane * 16;
    gll16(g, l);
    if (w < 4) gll16(g + 8192, l + 8192);
  }
  _Float16 zcur[4], znxt[4];
#pragma unroll
  for (int mt = 0; mt < 4; ++mt)
    zcur[mt] = zsT[(size_t)i0 * 2048 + e0 + wm * 64 + mt * 16 + l15];
  __syncthreads();

  f32x4 acc[4][3] = {};
  int buf = 0;

  for (int ip = 0; ip < 6; ++ip) {
    if (ip < 5) {
#pragma unroll
      for (int mt = 0; mt < 4; ++mt)
        znxt[mt] = zsT[(size_t)(i0 + ip + 1) * 2048 + e0 + wm * 64 + mt * 16 + l15];
    }
    half8 zv[4];
#pragma unroll
    for (int mt = 0; mt < 4; ++mt) {
      _Float16 zc = zcur[mt];
      zv[mt] = (half8){zc, zc, zc, zc, zc, zc, zc, zc};
    }
#pragma unroll
    for (int k6 = 0; k6 < 6; ++k6) {
      int ks = ip * 6 + k6;
      if (ks < 35) {
        const char* g = (const char*)btl + (size_t)(sg0 + ks + 1) * 12288 + w * 1024 + lane * 16;
        char* l = (char*)Bl + (buf ^ 1) * 12288 + w * 1024 + lane * 16;
        gll16(g, l);
        if (w < 4) gll16(g + 8192, l + 8192);
      }
      half8 av[4];
#pragma unroll
      for (int mt = 0; mt < 4; ++mt) {
        half8 hv = *(const half8*)(Al + (((k6 * 4 + q4) * 128) + wm * 64 + mt * 16 + l15) * 8);
        av[mt] = hv * zv[mt];
      }
#pragma unroll
      for (int nt = 0; nt < 3; ++nt) {
        half8 bv = *(const half8*)(Bl + buf * 6144 + ((q4 * 192) + wn * 48 + nt * 16 + l15) * 8);
#pragma unroll
        for (int mt = 0; mt < 4; ++mt)
          acc[mt][nt] = __builtin_amdgcn_mfma_f32_16x16x32_f16(av[mt], bv, acc[mt][nt], 0, 0, 0);
      }
      __syncthreads();
      buf ^= 1;
    }
#pragma unroll
    for (int mt = 0; mt < 4; ++mt) zcur[mt] = znxt[mt];
  }

#pragma unroll
  for (int mt = 0; mt < 4; ++mt)
#pragma unroll
    for (int nt = 0; nt < 3; ++nt) {
      int o = wn * 48 + nt * 16 + l15;
#pragma unroll
      for (int r = 0; r < 4; ++r) {
        int e = e0 + wm * 64 + mt * 16 + q4 * 4 + r;
        partial[((size_t)s * 2048 + e) * 192 + o] = (_Float16)acc[mt][nt][r];
      }
    }
}

__global__ void k_reduce(const _Float16* __restrict__ partial, const float* __restrict__ nodeMsg,
                         const int* __restrict__ ei, float* __restrict__ agg) {
  int idx = blockIdx.x * 256 + threadIdx.x;
  int e = idx / 192, o = idx - e * 192;
  float ssum = nodeMsg[(size_t)ei[e] * 192 + o];
#pragma unroll
  for (int sc = 0; sc < 32; ++sc) ssum += (float)partial[(size_t)sc * 393216 + idx];
  atomicAdd(&agg[(size_t)ei[2048 + e] * 192 + o], ssum);
}

__global__ void k_final(const float* __restrict__ z, const float* __restrict__ ow,
                        const float* __restrict__ ob, float* __restrict__ outp) {
  int t = blockIdx.x * 256 + threadIdx.x;
  if (t >= 2048) return;
  int n = t >> 1, c = t & 1;
  float acc = ob[c];
#pragma unroll 8
  for (int j = 0; j < 192; ++j) acc += z[n * 192 + j] * ow[j * 2 + c];
  outp[t] = acc;
}

// ---------------- launch ----------------
extern "C" void kernel_launch(void* const* d_in, const int* in_sizes, int n_in,
                              void* d_out, int out_size, void* d_ws, size_t ws_size,
                              hipStream_t stream) {
  const float* x      = (const float*)d_in[0];
  const int*   ei     = (const int*)  d_in[1];
  const float* eattr  = (const float*)d_in[2];
  const float* cheb_w = (const float*)d_in[4];
  const float* cheb_b = (const float*)d_in[5];
  const float* eenc_w = (const float*)d_in[6];
  const float* eenc_b = (const float*)d_in[7];
  const float* nn1_w  = (const float*)d_in[8];
  const float* nn1_b  = (const float*)d_in[9];
  const float* nn2_w  = (const float*)d_in[10];
  const float* nn2_b  = (const float*)d_in[11];
  const float* root_w = (const float*)d_in[12];
  const float* conv_b = (const float*)d_in[13];
  const float* ln_g   = (const float*)d_in[14];
  const float* ln_bb  = (const float*)d_in[15];
  const float* out_w  = (const float*)d_in[16];
  const float* out_b  = (const float*)d_in[17];
  float* outp = (float*)d_out;
  (void)in_sizes; (void)n_in; (void)out_size; (void)ws_size;

  char* p = (char*)d_ws;
  _Float16* nn2t = (_Float16*)p; p += (size_t)4 * 4608 * 1536 * 2;   // 56.6 MB
  _Float16* nn1t = (_Float16*)p; p += (size_t)4 * 36864 * 2;
  _Float16* b2t  = (_Float16*)p; p += (size_t)4 * 36864 * 2;
  _Float16* rwt  = (_Float16*)p; p += (size_t)4 * 36864 * 2;
  _Float16* h2p4 = (_Float16*)p; p += (size_t)4 * 393216 * 2;
  _Float16* zsT  = (_Float16*)p; p += (size_t)393216 * 2;
  _Float16* part = (_Float16*)p; p += (size_t)32 * 393216 * 2;
  float* nodeMsg = (float*)p; p += (size_t)196608 * 4;
  float* Tx   = (float*)p; p += 5 * 4096 * 4;
  float* h    = (float*)p; p += 196608 * 4;
  float* zA   = (float*)p; p += 196608 * 4;
  float* zB   = (float*)p; p += 196608 * 4;
  float* ea   = (float*)p; p += 393216 * 4;
  float* agg  = (float*)p; p += 196608 * 4;

  hipFuncSetAttribute(reinterpret_cast<const void*>(&k_big2),
                      hipFuncAttributeMaxDynamicSharedMemorySize, 73728);
  hipFuncSetAttribute(reinterpret_cast<const void*>(&k_ng),
                      hipFuncAttributeMaxDynamicSharedMemorySize, 73728);

  k_cheb_all<<<1, 1024, 0, stream>>>(x, ei, Tx);
  k_cheb_out<<<1024, 192, 0, stream>>>(Tx, cheb_w, cheb_b, h);
  k_ea<<<2048, 192, 0, stream>>>(eattr, eenc_w, eenc_b, ea);
  k_tr<<<dim3(780, 3), 256, 0, stream>>>(nn2_w, nn1_w, nn2_b, root_w, nn2t, nn1t, b2t, rwt);
  // h2 for all 4 layers (A = ea, layer = blockIdx.y)
  k_ng<<<dim3(16, 4), 256, 73728, stream>>>(ea, nn1t, nn1_b, h2p4,
                                            nullptr, nullptr, nullptr, nullptr, nullptr, nullptr, 0, 0);

  float* zsrc = h; float* zdst = zA;
  for (int l = 0; l < 4; ++l) {
    k_edge<<<32, 256, 0, stream>>>(ei, zsrc, zsT, agg);
    k_ng<<<dim3(8, 1), 256, 73728, stream>>>(zsrc, b2t + (size_t)l * 36864, nullptr, nullptr,
                                             nullptr, nullptr, nullptr, nullptr, nullptr, nodeMsg, 1, 0);
    k_big2<<<dim3(32, 16), 512, 73728, stream>>>(h2p4 + (size_t)l * 393216,
                                                 nn2t + (size_t)l * 7077888, zsT, part);
    k_reduce<<<1536, 256, 0, stream>>>(part, nodeMsg, ei, agg);
    const float* lg = ln_g + (size_t)((l == 3) ? 0 : (l + 1)) * 192;
    const float* lb = ln_bb + (size_t)((l == 3) ? 0 : (l + 1)) * 192;
    k_ng<<<dim3(8, 1), 256, 73728, stream>>>(zsrc, rwt + (size_t)l * 36864, nullptr, nullptr,
                                             agg, conv_b + (size_t)l * 192, h, lg, lb, zdst, 2, (l == 0) ? 0 : 1);
    zsrc = zdst; zdst = (zdst == zA) ? zB : zA;
  }
  k_final<<<8, 256, 0, stream>>>(zsrc, out_w, out_b, outp);
}

// Round 4
// 343.101 us; speedup vs baseline: 2.1997x; 2.1997x over previous
//
#include <hip/hip_runtime.h>
#include <stdint.h>

typedef _Float16 half8 __attribute__((ext_vector_type(8)));
typedef float f32x4 __attribute__((ext_vector_type(4)));

typedef const __attribute__((address_space(1))) void* gptr_t;
typedef __attribute__((address_space(3))) void* lptr_t;
static __device__ __forceinline__ void gll16(const void* g, void* l) {
  __builtin_amdgcn_global_load_lds((gptr_t)(unsigned long long)g,
                                   (lptr_t)(unsigned int)(unsigned long long)l,
                                   16, 0, 0);
}

// ---------------- Cheb chain (block 0) + M-build (blocks 1..4) ----------------
// M[l] = [eenc_w @ nn1_w[l] (4 rows); eenc_b @ nn1_w[l] + nn1_b[l] (row 4)]  [5x192]
__global__ __launch_bounds__(1024)
void k_chebM(const float* __restrict__ x, const int* __restrict__ ei,
             const float* __restrict__ eenc_w, const float* __restrict__ eenc_b,
             const float* __restrict__ nn1_w, const float* __restrict__ nn1_b,
             float* __restrict__ Tx, float* __restrict__ Mbuf) {
  if (blockIdx.x == 0) {
    __shared__ float deg[1024];
    __shared__ float wn[2048];
    __shared__ float T0[4096], T1[4096], yv[4096];
    int t = threadIdx.x;
    deg[t] = 0.f;
    __syncthreads();
    atomicAdd(&deg[ei[t]], 1.f);
    atomicAdd(&deg[ei[1024 + t]], 1.f);
    __syncthreads();
    for (int e = t; e < 2048; e += 1024) {
      int s = ei[e], d = ei[2048 + e];
      float ds = deg[s], dd = deg[d];
      float a = ds > 0.f ? 1.f / sqrtf(fmaxf(ds, 1.f)) : 0.f;
      float b = dd > 0.f ? 1.f / sqrtf(fmaxf(dd, 1.f)) : 0.f;
      wn[e] = -a * b;
    }
    float4 xv = ((const float4*)x)[t];
    ((float4*)T0)[t] = xv;
    ((float4*)Tx)[t] = xv;
    __syncthreads();
    float* cur = T0; float* nxt = T1;
    for (int rec = 0; rec < 4; ++rec) {
      ((float4*)yv)[t] = make_float4(0.f, 0.f, 0.f, 0.f);
      __syncthreads();
      for (int e = t; e < 2048; e += 1024) {
        int s = ei[e], d = ei[2048 + e];
        float wv = wn[e];
#pragma unroll
        for (int c = 0; c < 4; ++c) atomicAdd(&yv[d * 4 + c], wv * cur[s * 4 + c]);
      }
      __syncthreads();
      float a = (rec == 0) ? 1.f : 2.f;
      float4 y4 = ((float4*)yv)[t];
      float4 p4 = ((float4*)nxt)[t];
      float4 n4;
      n4.x = a * y4.x - (rec ? p4.x : 0.f);
      n4.y = a * y4.y - (rec ? p4.y : 0.f);
      n4.z = a * y4.z - (rec ? p4.z : 0.f);
      n4.w = a * y4.w - (rec ? p4.w : 0.f);
      ((float4*)nxt)[t] = n4;
      ((float4*)(Tx + (rec + 1) * 4096))[t] = n4;
      __syncthreads();
      float* tmp = cur; cur = nxt; nxt = tmp;
    }
  } else {
    int l = blockIdx.x - 1;
    int t = threadIdx.x;
    if (t < 192) {
      float a0 = 0.f, a1 = 0.f, a2 = 0.f, a3 = 0.f, a4 = 0.f;
      const float* nw = nn1_w + (size_t)l * 36864 + t;
      for (int k = 0; k < 192; ++k) {
        float nv = nw[(size_t)k * 192];
        a0 += eenc_w[k] * nv;
        a1 += eenc_w[192 + k] * nv;
        a2 += eenc_w[384 + k] * nv;
        a3 += eenc_w[576 + k] * nv;
        a4 += eenc_b[k] * nv;
      }
      float* Ml = Mbuf + l * 960;
      Ml[t] = a0; Ml[192 + t] = a1; Ml[384 + t] = a2; Ml[576 + t] = a3;
      Ml[768 + t] = a4 + nn1_b[l * 192 + t];
    }
  }
}

__global__ void k_cheb_out(const float* __restrict__ Tx, const float* __restrict__ cw,
                           const float* __restrict__ cb, float* __restrict__ h) {
  int n = blockIdx.x, o = threadIdx.x;
  float acc = cb[o];
#pragma unroll
  for (int k = 0; k < 5; ++k)
#pragma unroll
    for (int c = 0; c < 4; ++c)
      acc += Tx[k * 4096 + n * 4 + c] * cw[(k * 4 + c) * 192 + o];
  h[n * 192 + o] = acc;
}

// ---------------- P = M @ W2, k-split partials (the only HBM-heavy kernel) ----------------
// grid (36 col-tiles, 4 layers, 2 k-halves), 256 thr. Each thread: 4 cols, 5 accums.
__global__ __launch_bounds__(256)
void k_pb(const float* __restrict__ nn2_w, const float* __restrict__ Mbuf,
          float* __restrict__ Ppart) {
  int l = blockIdx.y, kc = blockIdx.z;
  int col = blockIdx.x * 1024 + threadIdx.x * 4;
  const float* W = nn2_w + (size_t)l * 7077888 + col;
  const float* Mp = Mbuf + l * 960 + kc * 96;
  f32x4 acc0 = {}, acc1 = {}, acc2 = {}, acc3 = {}, acc4 = {};
  const size_t rs = 36864;
  const float* Wk = W + (size_t)(kc * 96) * rs;
#pragma unroll 8
  for (int k = 0; k < 96; ++k) {
    f32x4 wv = *(const f32x4*)(Wk + (size_t)k * rs);
    acc0 += wv * Mp[k];
    acc1 += wv * Mp[192 + k];
    acc2 += wv * Mp[384 + k];
    acc3 += wv * Mp[576 + k];
    acc4 += wv * Mp[768 + k];
  }
  float* Pp = Ppart + ((size_t)(kc * 4 + l) * 5) * 36864 + col;
  *(f32x4*)(Pp) = acc0;
  *(f32x4*)(Pp + 36864) = acc1;
  *(f32x4*)(Pp + 2 * 36864) = acc2;
  *(f32x4*)(Pp + 3 * 36864) = acc3;
  *(f32x4*)(Pp + 4 * 36864) = acc4;
}

// ---------------- assemble B [192 k x 1152 n] f16 chunk-major ----------------
// n<960: B[i, c*192+o] = P[c, i*192+o] (+nn2_b for c==4); n>=960: root_w[k, n-960]
// layout: halfs (ck*1152 + n)*8 + (k&7), per-layer stride 221184 halfs
__global__ void k_stageB(const float* __restrict__ Ppart, const float* __restrict__ nn2_b,
                         const float* __restrict__ root_w, _Float16* __restrict__ Btl) {
  int ck = blockIdx.x, l = blockIdx.y, t = threadIdx.x;
  _Float16* out = Btl + (size_t)l * 221184 + ck * 9216;
#pragma unroll
  for (int it = 0; it < 5; ++it) {
    int n = it * 256 + t;
    if (n >= 1152) break;
    union { _Float16 h[8]; uint4 v; } u;
    if (n < 960) {
      int c = n / 192, o = n - c * 192;
      const float* P0 = Ppart + ((size_t)(0 * 4 + l) * 5 + c) * 36864;
      const float* P1 = Ppart + ((size_t)(1 * 4 + l) * 5 + c) * 36864;
#pragma unroll
      for (int j = 0; j < 8; ++j) {
        int io = (ck * 8 + j) * 192 + o;
        float val = P0[io] + P1[io];
        if (c == 4) val += nn2_b[(size_t)l * 36864 + io];
        u.h[j] = (_Float16)val;
      }
    } else {
      int o = n - 960;
#pragma unroll
      for (int j = 0; j < 8; ++j)
        u.h[j] = (_Float16)root_w[(size_t)l * 36864 + (ck * 8 + j) * 192 + o];
    }
    *(uint4*)(out + (size_t)n * 8) = u.v;
  }
}

// ---------------- Y = z @ B  (1024 x 1152, K=192) + zero agg ----------------
__global__ __launch_bounds__(256, 2)
void k_y(const float* __restrict__ z, const _Float16* __restrict__ Btl,
         float* __restrict__ Y, float* __restrict__ agg, int layer) {
  extern __shared__ _Float16 sm[];
  _Float16* Al = sm;           // 24 ck * 128 rows * 8 halfs = 48 KB
  _Float16* Bl = sm + 24576;   // 2 * 6144 halfs = 24 KB
  int t = threadIdx.x;
  int w = t >> 6, lane = t & 63, l15 = lane & 15, q4 = lane >> 4;
  int e0 = blockIdx.x * 128;
  int nb = blockIdx.y;
  const _Float16* Bt = Btl + (size_t)layer * 221184;

  // zero agg: 48 blocks x 4096 floats
  {
    int base4 = (blockIdx.y * 8 + blockIdx.x) * 1024;
    float4 zf = make_float4(0.f, 0.f, 0.f, 0.f);
#pragma unroll
    for (int q = 0; q < 4; ++q) ((float4*)agg)[base4 + q * 256 + t] = zf;
  }
  // prefetch B chunk ks=0 into buf 0 (wave w stages q=w sub-chunk, 3 KB)
  {
    const char* g = (const char*)Bt + (((size_t)w * 1152 + nb * 192) * 8) * 2;
    char* lb = (char*)Bl + w * 3072;
#pragma unroll
    for (int r = 0; r < 3; ++r) gll16(g + r * 1024 + lane * 16, lb + r * 1024 + lane * 16);
  }
  // stage A (f32 -> f16 chunk-major)
#pragma unroll
  for (int it = 0; it < 12; ++it) {
    int u = it * 256 + t;
    int row = u / 24, ck = u - row * 24;
    const float* ap = z + (size_t)(e0 + row) * 192 + ck * 8;
    float4 v0 = *(const float4*)ap;
    float4 v1 = *(const float4*)(ap + 4);
    union { _Float16 h[8]; uint4 v; } uu;
    uu.h[0] = (_Float16)v0.x; uu.h[1] = (_Float16)v0.y;
    uu.h[2] = (_Float16)v0.z; uu.h[3] = (_Float16)v0.w;
    uu.h[4] = (_Float16)v1.x; uu.h[5] = (_Float16)v1.y;
    uu.h[6] = (_Float16)v1.z; uu.h[7] = (_Float16)v1.w;
    *(uint4*)(Al + ((size_t)ck * 128 + row) * 8) = uu.v;
  }
  __syncthreads();

  f32x4 acc[2][12] = {};
  int buf = 0;
  for (int ks = 0; ks < 6; ++ks) {
    if (ks < 5) {
      const char* g = (const char*)Bt + (((size_t)((ks + 1) * 4 + w) * 1152 + nb * 192) * 8) * 2;
      char* lb = (char*)Bl + (buf ^ 1) * 12288 + w * 3072;
#pragma unroll
      for (int r = 0; r < 3; ++r) gll16(g + r * 1024 + lane * 16, lb + r * 1024 + lane * 16);
    }
    half8 av[2];
#pragma unroll
    for (int mt = 0; mt < 2; ++mt)
      av[mt] = *(const half8*)(Al + (((ks * 4 + q4) * 128) + w * 32 + mt * 16 + l15) * 8);
#pragma unroll
    for (int nt = 0; nt < 12; ++nt) {
      half8 bv = *(const half8*)(Bl + buf * 6144 + ((q4 * 192) + nt * 16 + l15) * 8);
#pragma unroll
      for (int mt = 0; mt < 2; ++mt)
        acc[mt][nt] = __builtin_amdgcn_mfma_f32_16x16x32_f16(av[mt], bv, acc[mt][nt], 0, 0, 0);
    }
    __syncthreads();
    buf ^= 1;
  }
#pragma unroll
  for (int mt = 0; mt < 2; ++mt)
#pragma unroll
    for (int nt = 0; nt < 12; ++nt) {
      int col = nt * 16 + l15;
#pragma unroll
      for (int r = 0; r < 4; ++r) {
        int row = e0 + w * 32 + mt * 16 + q4 * 4 + r;
        Y[(size_t)row * 1152 + nb * 192 + col] = acc[mt][nt][r];
      }
    }
}

// ---------------- per-edge combine + scatter ----------------
__global__ void k_scatter(const int* __restrict__ ei, const float* __restrict__ eattr,
                          const float* __restrict__ Y, float* __restrict__ agg) {
  int o = threadIdx.x;
  int e0 = blockIdx.x * 8;
#pragma unroll
  for (int q = 0; q < 8; ++q) {
    int e = e0 + q;
    int s = ei[e], d = ei[2048 + e];
    const float* yr = Y + (size_t)s * 1152;
    float u0 = eattr[e * 4], u1 = eattr[e * 4 + 1];
    float u2 = eattr[e * 4 + 2], u3 = eattr[e * 4 + 3];
    float m = yr[o] * u0 + yr[192 + o] * u1 + yr[384 + o] * u2 + yr[576 + o] * u3 + yr[768 + o];
    atomicAdd(&agg[(size_t)d * 192 + o], m);
  }
}

// ---------------- node update: h' = (res?h:0) + agg + Yroot + cb; z' = relu(LN(h')) ----------------
__global__ void k_node(const float* __restrict__ hprev, const float* __restrict__ agg,
                       const float* __restrict__ Y, const float* __restrict__ cb,
                       const float* __restrict__ lg, const float* __restrict__ lb,
                       float* __restrict__ hnext, float* __restrict__ znext, int res) {
  __shared__ float r1[192], r2[192];
  __shared__ float mus, vars;
  int n = blockIdx.x, t = threadIdx.x;
  float v = agg[n * 192 + t] + Y[(size_t)n * 1152 + 960 + t] + cb[t];
  if (res) v += hprev[n * 192 + t];
  hnext[n * 192 + t] = v;
  r1[t] = v; r2[t] = v * v;
  __syncthreads();
  if (t < 96) { r1[t] += r1[t + 96]; r2[t] += r2[t + 96]; } __syncthreads();
  if (t < 48) { r1[t] += r1[t + 48]; r2[t] += r2[t + 48]; } __syncthreads();
  if (t < 24) { r1[t] += r1[t + 24]; r2[t] += r2[t + 24]; } __syncthreads();
  if (t < 12) { r1[t] += r1[t + 12]; r2[t] += r2[t + 12]; } __syncthreads();
  if (t < 6)  { r1[t] += r1[t + 6];  r2[t] += r2[t + 6];  } __syncthreads();
  if (t == 0) {
    float s1 = r1[0] + r1[1] + r1[2] + r1[3] + r1[4] + r1[5];
    float s2 = r2[0] + r2[1] + r2[2] + r2[3] + r2[4] + r2[5];
    float mu = s1 / 192.f;
    mus = mu; vars = s2 / 192.f - mu * mu;
  }
  __syncthreads();
  float o = (v - mus) * rsqrtf(vars + 1e-5f) * lg[t] + lb[t];
  znext[n * 192 + t] = fmaxf(o, 0.f);
}

__global__ void k_final(const float* __restrict__ z, const float* __restrict__ ow,
                        const float* __restrict__ ob, float* __restrict__ outp) {
  int t = blockIdx.x * 256 + threadIdx.x;
  if (t >= 2048) return;
  int n = t >> 1, c = t & 1;
  float acc = ob[c];
#pragma unroll 8
  for (int j = 0; j < 192; ++j) acc += z[n * 192 + j] * ow[j * 2 + c];
  outp[t] = acc;
}

// ---------------- launch ----------------
extern "C" void kernel_launch(void* const* d_in, const int* in_sizes, int n_in,
                              void* d_out, int out_size, void* d_ws, size_t ws_size,
                              hipStream_t stream) {
  const float* x      = (const float*)d_in[0];
  const int*   ei     = (const int*)  d_in[1];
  const float* eattr  = (const float*)d_in[2];
  const float* cheb_w = (const float*)d_in[4];
  const float* cheb_b = (const float*)d_in[5];
  const float* eenc_w = (const float*)d_in[6];
  const float* eenc_b = (const float*)d_in[7];
  const float* nn1_w  = (const float*)d_in[8];
  const float* nn1_b  = (const float*)d_in[9];
  const float* nn2_w  = (const float*)d_in[10];
  const float* nn2_b  = (const float*)d_in[11];
  const float* root_w = (const float*)d_in[12];
  const float* conv_b = (const float*)d_in[13];
  const float* ln_g   = (const float*)d_in[14];
  const float* ln_bb  = (const float*)d_in[15];
  const float* out_w  = (const float*)d_in[16];
  const float* out_b  = (const float*)d_in[17];
  float* outp = (float*)d_out;
  (void)in_sizes; (void)n_in; (void)out_size; (void)ws_size;

  char* p = (char*)d_ws;
  _Float16* Btl = (_Float16*)p; p += (size_t)4 * 221184 * 2;     // 1.77 MB
  float* Ppart  = (float*)p;    p += (size_t)2 * 4 * 5 * 36864 * 4;  // 5.9 MB
  float* Mbuf   = (float*)p;    p += 4 * 5 * 192 * 4;
  float* Tx     = (float*)p;    p += 5 * 4096 * 4;
  float* Y      = (float*)p;    p += (size_t)1024 * 1152 * 4;    // 4.7 MB
  float* h      = (float*)p;    p += 196608 * 4;
  float* hA     = (float*)p;    p += 196608 * 4;
  float* hB     = (float*)p;    p += 196608 * 4;
  float* zA     = (float*)p;    p += 196608 * 4;
  float* zB     = (float*)p;    p += 196608 * 4;
  float* agg    = (float*)p;    p += 196608 * 4;

  hipFuncSetAttribute(reinterpret_cast<const void*>(&k_y),
                      hipFuncAttributeMaxDynamicSharedMemorySize, 73728);

  k_chebM<<<5, 1024, 0, stream>>>(x, ei, eenc_w, eenc_b, nn1_w, nn1_b, Tx, Mbuf);
  k_cheb_out<<<1024, 192, 0, stream>>>(Tx, cheb_w, cheb_b, h);
  k_pb<<<dim3(36, 4, 2), 256, 0, stream>>>(nn2_w, Mbuf, Ppart);
  k_stageB<<<dim3(24, 4), 256, 0, stream>>>(Ppart, nn2_b, root_w, Btl);

  float* zcur = h;
  float* hcur = h;  // unused when res==0
  float* hbufs[2] = {hA, hB};
  float* zbufs[2] = {zA, zB};
  for (int l = 0; l < 4; ++l) {
    k_y<<<dim3(8, 6), 256, 73728, stream>>>(zcur, Btl, Y, agg, l);
    k_scatter<<<256, 192, 0, stream>>>(ei, eattr, Y, agg);
    const float* lg = ln_g + (size_t)((l == 3) ? 0 : (l + 1)) * 192;
    const float* lb = ln_bb + (size_t)((l == 3) ? 0 : (l + 1)) * 192;
    k_node<<<1024, 192, 0, stream>>>(hcur, agg, Y, conv_b + (size_t)l * 192,
                                     lg, lb, hbufs[l & 1], zbufs[l & 1], (l == 0) ? 0 : 1);
    hcur = hbufs[l & 1];
    zcur = zbufs[l & 1];
  }
  k_final<<<8, 256, 0, stream>>>(zcur, out_w, out_b, outp);
}